// Round 21
// baseline (265.751 us; speedup 1.0000x reference)
//
#include <hip/hip_runtime.h>
#include <hip/hip_fp16.h>
#include <hip/hip_cooperative_groups.h>

namespace cg = cooperative_groups;

// ---------------------------------------------------------------------------
// CrowdGNN: 2-layer GCN, N=500k nodes, E=8M edges (+ implicit self loops).
// Round-21 = round-20 champion (179.2us) + COOPERATIVE FUSION of the three
// agg kernels (deg/dinv/y -> layer1+MLP -> layer2) into one kernel with
// grid.sync() between phases. Eliminates 2 kernel-boundary drain/fill +
// graph-node gaps; weights loaded once. Phase bodies byte-identical to
// round-20. Grid 512x512 bin-strided (2 blocks/CU co-resident, LB(512,4),
// ~14.5KB LDS). Host checks occupancy + launch error -> falls back to the
// three separate kernels (identical math) if cooperative launch refuses.
// Partition (16K-edge blocks, bin-in-payload LDS staging) unchanged.
// Fixed-point: wq q11 in slot hi (bin10|wq11); y fp16; acc q22/q20.
// ---------------------------------------------------------------------------

typedef unsigned long long u64;
typedef long long ll2 __attribute__((ext_vector_type(2)));

#define NPB_SHIFT 9
#define NPB 512
#define MAX_BINS 1024
#define PART_THREADS 1024
#define PART_EPT 16
#define PART_CHUNK (PART_THREADS * PART_EPT)   // 16384 edges per block
#define AGG_THREADS 512
#define FUSE_THREADS 512
#define FUSE_BLOCKS 512

#define Q11      2048.0f
#define INV11    (1.0f / 2048.0f)
#define A1_INV   (1.0f / 4194304.0f)   // q22
#define A2_INV   (1.0f / 1048576.0f)   // q20
#define BIAS     (1u << 25)            // per-edge field bias, > max|c|=2^24.4
#define WQMASK   0x7FFu

struct h4 { __half2 a, b; };

__device__ __forceinline__ float4 h4_to_f4(h4 v) {
    float2 lo = __half22float2(v.a);
    float2 hi = __half22float2(v.b);
    return make_float4(lo.x, lo.y, hi.x, hi.y);
}

// One launch: zero gCnt (all threads) + int64/int32 detect (block 0).
__global__ __launch_bounds__(1024)
void k_prep(const unsigned int* __restrict__ idx_words, int nCheck, int* flag,
            int* __restrict__ gCnt, int B, int nBlocks) {
    int gid = blockIdx.x * 1024 + threadIdx.x;
    for (int i = gid; i < B; i += nBlocks * 1024) gCnt[i] = 0;
    if (blockIdx.x == 0) {
        __shared__ int cnt;
        if (threadIdx.x == 0) cnt = 0;
        __syncthreads();
        int local = 0;
        for (int i = threadIdx.x; i < nCheck; i += 1024)
            local += (idx_words[2 * i + 1] != 0u) ? 1 : 0;
        if (local) atomicAdd(&cnt, local);
        __syncthreads();
        if (threadIdx.x == 0) *flag = (cnt < 8) ? 1 : 0;
    }
}

// Bin-sorted-staging partition; payload = [bin10|wq11]<<32 | [dl9|src23].
__global__ __launch_bounds__(PART_THREADS)
void k_partition(const void* __restrict__ idx, const float* __restrict__ ew,
                 int* __restrict__ gCnt, u64* __restrict__ slots,
                 int E, int B, int cap, const int* __restrict__ flag) {
    __shared__ int lcnt[MAX_BINS];
    __shared__ int lbase[MAX_BINS];
    __shared__ int lstart[MAX_BINS];
    __shared__ u64 sPay[PART_CHUNK];
    __shared__ int waveSum[PART_THREADS / 64];

    const bool is64 = (*flag != 0);
    const int tid = threadIdx.x;
    for (int i = tid; i < MAX_BINS; i += PART_THREADS) lcnt[i] = 0;
    __syncthreads();

    const int base_e = blockIdx.x * PART_CHUNK;
    const int nValid = min(PART_CHUNK, E - base_e);

    u64 pay[PART_EPT];
    int r_[PART_EPT];
#pragma unroll
    for (int i = 0; i < PART_EPT; ++i) {
        int e = base_e + i * PART_THREADS + tid;
        r_[i] = -1;
        if (e < E) {
            int s, d;
            if (is64) {
                const long long* p = (const long long*)idx;
                s = (int)__builtin_nontemporal_load(p + e);
                d = (int)__builtin_nontemporal_load(p + (long long)E + e);
            } else {
                const int* p = (const int*)idx;
                s = __builtin_nontemporal_load(p + e);
                d = __builtin_nontemporal_load(p + E + e);
            }
            float w = __builtin_nontemporal_load(ew + e);
            int bin = d >> NPB_SHIFT;
            unsigned wq = min((unsigned)__float2int_rn(w * Q11), 2047u);
            unsigned hi = ((unsigned)bin << 11) | wq;            // bin10|wq11
            unsigned pk = ((unsigned)(d & (NPB - 1)) << 23) | (unsigned)s;
            pay[i] = ((u64)hi << 32) | pk;
            r_[i] = atomicAdd(&lcnt[bin], 1);
        }
    }
    __syncthreads();

    {
        const int lane = tid & 63, wid = tid >> 6;
        const int v = lcnt[tid];
        int inc = v;
#pragma unroll
        for (int off = 1; off < 64; off <<= 1) {
            int t = __shfl_up(inc, off, 64);
            if (lane >= off) inc += t;
        }
        if (lane == 63) waveSum[wid] = inc;
        __syncthreads();
        if (wid == 0) {
            const int NW = PART_THREADS / 64;
            int wv = (lane < NW) ? waveSum[lane] : 0;
            int winc = wv;
#pragma unroll
            for (int off = 1; off < NW; off <<= 1) {
                int t = __shfl_up(winc, off, 64);
                if (lane >= off) winc += t;
            }
            if (lane < NW) waveSum[lane] = winc - wv;
        }
        __syncthreads();
        lstart[tid] = inc - v + waveSum[wid];
        lbase[tid] = (v > 0 && tid < B) ? atomicAdd(&gCnt[tid], v) : 0;
    }
    __syncthreads();

#pragma unroll
    for (int i = 0; i < PART_EPT; ++i) {
        if (r_[i] >= 0) {
            int bin = (int)(pay[i] >> 43);
            sPay[lstart[bin] + r_[i]] = pay[i];
        }
    }
    __syncthreads();

    for (int k = tid; k < nValid; k += PART_THREADS) {
        u64 v = sPay[k];
        int bin = (int)(v >> 43);
        long long pos = (long long)lbase[bin] + (k - lstart[bin]);
        if (pos < cap) slots[(size_t)bin * cap + pos] = v;
    }
}

// 4-wide slot fetch, CACHED loads.
__device__ __forceinline__ void load4(const u64* __restrict__ sp, int j, int c,
                                      u64& v0, u64& v1, u64& v2, u64& v3) {
    v0 = v1 = v2 = v3 = 0;
    if (j + 3 < c) {
        ll2 q0 = *((const ll2*)(sp + j));
        ll2 q1 = *((const ll2*)(sp + j) + 1);
        v0 = (u64)q0.x; v1 = (u64)q0.y; v2 = (u64)q1.x; v3 = (u64)q1.y;
    } else if (j < c) {
        v0 = sp[j];
        if (j + 1 < c) v1 = sp[j + 1];
        if (j + 2 < c) v2 = sp[j + 2];
    }
}

// 8-wide slot fetch; tail zero-filled.
__device__ __forceinline__ void load8(const u64* __restrict__ sp, int j, int c,
                                      u64* __restrict__ v) {
    if (j + 7 < c) {
#pragma unroll
        for (int q = 0; q < 4; ++q) {
            ll2 t = *((const ll2*)(sp + j) + q);
            v[2 * q]     = (u64)t.x;
            v[2 * q + 1] = (u64)t.y;
        }
    } else {
#pragma unroll
        for (int q = 0; q < 8; ++q)
            v[q] = (j + q < c) ? sp[j + q] : 0ULL;
    }
}

// ------------------- phase bodies (shared by fused & split) ----------------

__device__ __forceinline__ void deg_body(
        const u64* __restrict__ slots, const int* __restrict__ gCnt,
        const float4* __restrict__ x, float* __restrict__ dinv,
        h4* __restrict__ y, int* __restrict__ rowCnt, int N, int cap,
        int b, unsigned* degLds, int nThreads) {
    for (int t = threadIdx.x; t < NPB; t += nThreads) degLds[t] = 0u;
    __syncthreads();
    const int c = min(gCnt[b], cap);
    const u64* sp = slots + (size_t)b * cap;
    const int CH = nThreads * 8;
    for (int base = 0; base < c; base += CH) {
        int j = base + (threadIdx.x << 3);
        u64 v[8];
        load8(sp, j, c, v);
#pragma unroll
        for (int q = 0; q < 8; ++q) {
            if (j + q < c)
                atomicAdd(&degLds[((unsigned)v[q]) >> 23],
                          (1u << 20) | ((unsigned)(v[q] >> 32) & WQMASK));
        }
    }
    __syncthreads();
    for (int t = threadIdx.x; t < NPB; t += nThreads) {
        int n = (b << NPB_SHIFT) + t;
        if (n < N) {
            unsigned dc = degLds[t];
            float di = rsqrtf(1.0f + (float)(dc & 0xFFFFFu) * INV11);
            dinv[n] = di;
            rowCnt[n] = (int)(dc >> 20);
            float4 xv = x[n];
            h4 hv;
            hv.a = __floats2half2_rn(xv.x * di, xv.y * di);
            hv.b = __floats2half2_rn(xv.z * di, xv.w * di);
            y[n] = hv;
        }
    }
    __syncthreads();
}

__device__ __forceinline__ void layer1_body(
        const u64* __restrict__ slots, const int* __restrict__ gCnt,
        const float* __restrict__ dinv, const h4* __restrict__ yh,
        const int* __restrict__ rowCnt, float* __restrict__ z, int N, int cap,
        int b, u64 (*acc2)[2], float* dLds,
        const float* sW1, const float* sb1, const float* sW2, int nThreads) {
    for (int t = threadIdx.x; t < NPB; t += nThreads) {
        acc2[t][0] = 0ULL; acc2[t][1] = 0ULL;
        int n = (b << NPB_SHIFT) + t;
        dLds[t] = (n < N) ? dinv[n] : 0.0f;
    }
    __syncthreads();
    const int c = min(gCnt[b], cap);
    const u64* sp = slots + (size_t)b * cap;
    const int CH = nThreads * 4;
    for (int base = 0; base < c; base += CH) {
        int j = base + (threadIdx.x << 2);
        u64 v0, v1, v2, v3;
        load4(sp, j, c, v0, v1, v2, v3);
        unsigned pk0 = (unsigned)v0, pk1 = (unsigned)v1,
                 pk2 = (unsigned)v2, pk3 = (unsigned)v3;
        float w0 = (float)((unsigned)(v0 >> 32) & WQMASK) * 2048.0f;
        float w1 = (float)((unsigned)(v1 >> 32) & WQMASK) * 2048.0f;
        float w2 = (float)((unsigned)(v2 >> 32) & WQMASK) * 2048.0f;
        float w3 = (float)((unsigned)(v3 >> 32) & WQMASK) * 2048.0f;
        h4 g0 = yh[pk0 & 0x7FFFFF];
        h4 g1 = yh[pk1 & 0x7FFFFF];
        h4 g2 = yh[pk2 & 0x7FFFFF];
        h4 g3 = yh[pk3 & 0x7FFFFF];
        float4 f0 = h4_to_f4(g0), f1 = h4_to_f4(g1),
               f2 = h4_to_f4(g2), f3 = h4_to_f4(g3);
        int d0 = pk0 >> 23, d1 = pk1 >> 23, d2 = pk2 >> 23, d3 = pk3 >> 23;
#define PACK2(wf, fa, fb) \
        (((u64)(unsigned)(__float2int_rn((wf) * (fb)) + (int)BIAS) << 32) | \
          (u64)(unsigned)(__float2int_rn((wf) * (fa)) + (int)BIAS))
        if (j < c) {
            atomicAdd(&acc2[d0][0], PACK2(w0, f0.x, f0.y));
            atomicAdd(&acc2[d0][1], PACK2(w0, f0.z, f0.w));
        }
        if (j + 1 < c) {
            atomicAdd(&acc2[d1][0], PACK2(w1, f1.x, f1.y));
            atomicAdd(&acc2[d1][1], PACK2(w1, f1.z, f1.w));
        }
        if (j + 2 < c) {
            atomicAdd(&acc2[d2][0], PACK2(w2, f2.x, f2.y));
            atomicAdd(&acc2[d2][1], PACK2(w2, f2.z, f2.w));
        }
        if (j + 3 < c) {
            atomicAdd(&acc2[d3][0], PACK2(w3, f3.x, f3.y));
            atomicAdd(&acc2[d3][1], PACK2(w3, f3.z, f3.w));
        }
#undef PACK2
    }
    __syncthreads();
    for (int t = threadIdx.x; t < NPB; t += nThreads) {
        int n = (b << NPB_SHIFT) + t;
        if (n >= N) continue;
        unsigned cb = (unsigned)rowCnt[n] * BIAS;
        u64 p01 = acc2[t][0], p23 = acc2[t][1];
        int a0 = (int)((unsigned)(p01 & 0xFFFFFFFFu) - cb);
        int a1 = (int)((unsigned)(p01 >> 32) - cb);
        int a2 = (int)((unsigned)(p23 & 0xFFFFFFFFu) - cb);
        int a3 = (int)((unsigned)(p23 >> 32) - cb);
        float di = dLds[t];
        float4 yv = h4_to_f4(yh[n]);
        float ax = di * (yv.x + (float)a0 * A1_INV);
        float ay = di * (yv.y + (float)a1 * A1_INV);
        float az = di * (yv.z + (float)a2 * A1_INV);
        float aw = di * (yv.w + (float)a3 * A1_INV);
        float sacc = 0.0f;
#pragma unroll
        for (int k = 0; k < 16; ++k) {
            float h = ax * sW1[k] + ay * sW1[16 + k] + az * sW1[32 + k]
                    + aw * sW1[48 + k] + sb1[k];
            sacc += fmaxf(h, 0.0f) * sW2[k];
        }
        z[n] = sacc * di;
    }
    __syncthreads();
}

__device__ __forceinline__ void layer2_body(
        const u64* __restrict__ slots, const int* __restrict__ gCnt,
        const float* __restrict__ dinv, const float* __restrict__ z,
        const float* __restrict__ b2, float* __restrict__ out, int N, int cap,
        int b, int* accs, float* dLds, int nThreads) {
    for (int t = threadIdx.x; t < NPB; t += nThreads) {
        accs[t] = 0;
        int n = (b << NPB_SHIFT) + t;
        dLds[t] = (n < N) ? dinv[n] : 0.0f;
    }
    __syncthreads();
    const int c = min(gCnt[b], cap);
    const u64* sp = slots + (size_t)b * cap;
    const int CH = nThreads * 8;
    for (int base = 0; base < c; base += CH) {
        int j = base + (threadIdx.x << 3);
        u64 v[8];
        load8(sp, j, c, v);
        float zf[8];
#pragma unroll
        for (int q = 0; q < 8; ++q)
            zf[q] = z[(unsigned)v[q] & 0x7FFFFF];
#pragma unroll
        for (int q = 0; q < 8; ++q) {
            atomicAdd(&accs[((unsigned)v[q]) >> 23],
                      __float2int_rn((float)((unsigned)(v[q] >> 32) & WQMASK)
                                     * zf[q] * 512.0f));
        }
    }
    __syncthreads();
    const float bb2 = b2[0];
    for (int t = threadIdx.x; t < NPB; t += nThreads) {
        int n = (b << NPB_SHIFT) + t;
        if (n < N) out[n] = dLds[t] * (z[n] + (float)accs[t] * A2_INV) + bb2;
    }
    __syncthreads();
}

// ---------------- fused cooperative agg (deg -> layer1 -> layer2) ---------
__global__ __launch_bounds__(FUSE_THREADS, 4)
void k_agg(const u64* __restrict__ slots, const int* __restrict__ gCnt,
           const float4* __restrict__ x, const float* __restrict__ W1,
           const float* __restrict__ b1, const float* __restrict__ W2,
           const float* __restrict__ b2, float* __restrict__ dinv,
           h4* __restrict__ y, int* __restrict__ rowCnt, float* __restrict__ z,
           float* __restrict__ out, int N, int cap, int B) {
    cg::grid_group grid = cg::this_grid();
    __shared__ unsigned degLds[NPB];
    __shared__ u64 acc2[NPB][2];
    __shared__ float dLds[NPB];
    __shared__ int accs[NPB];
    __shared__ float sW1[64], sb1[16], sW2[16];
    if (threadIdx.x < 64) sW1[threadIdx.x] = W1[threadIdx.x];
    if (threadIdx.x < 16) {
        sb1[threadIdx.x] = b1[threadIdx.x];
        sW2[threadIdx.x] = W2[threadIdx.x];
    }
    // Phase 1: deg/dinv/y
    for (int b = blockIdx.x; b < B; b += gridDim.x)
        deg_body(slots, gCnt, x, dinv, y, rowCnt, N, cap, b, degLds, FUSE_THREADS);
    grid.sync();
    // Phase 2: layer1 + fused MLP
    for (int b = blockIdx.x; b < B; b += gridDim.x)
        layer1_body(slots, gCnt, dinv, (const h4*)y, rowCnt, z, N, cap, b,
                    acc2, dLds, sW1, sb1, sW2, FUSE_THREADS);
    grid.sync();
    // Phase 3: layer2
    for (int b = blockIdx.x; b < B; b += gridDim.x)
        layer2_body(slots, gCnt, dinv, z, b2, out, N, cap, b, accs, dLds,
                    FUSE_THREADS);
}

// ---------------- split agg kernels (fallback path) ------------------------
__global__ __launch_bounds__(AGG_THREADS, 8)
void k_deg_dinv(const u64* __restrict__ slots, const int* __restrict__ gCnt,
                const float4* __restrict__ x, float* __restrict__ dinv,
                h4* __restrict__ y, int* __restrict__ rowCnt, int N, int cap) {
    __shared__ unsigned degLds[NPB];
    deg_body(slots, gCnt, x, dinv, y, rowCnt, N, cap, blockIdx.x, degLds,
             AGG_THREADS);
}

__global__ __launch_bounds__(AGG_THREADS, 4)
void k_layer1(const u64* __restrict__ slots, const int* __restrict__ gCnt,
              const float* __restrict__ dinv, const h4* __restrict__ yh,
              const int* __restrict__ rowCnt, const float* __restrict__ W1,
              const float* __restrict__ b1, const float* __restrict__ W2,
              float* __restrict__ z, int N, int cap) {
    __shared__ u64 acc2[NPB][2];
    __shared__ float dLds[NPB];
    __shared__ float sW1[64], sb1[16], sW2[16];
    if (threadIdx.x < 64) sW1[threadIdx.x] = W1[threadIdx.x];
    if (threadIdx.x < 16) {
        sb1[threadIdx.x] = b1[threadIdx.x];
        sW2[threadIdx.x] = W2[threadIdx.x];
    }
    layer1_body(slots, gCnt, dinv, yh, rowCnt, z, N, cap, blockIdx.x,
                acc2, dLds, sW1, sb1, sW2, AGG_THREADS);
}

__global__ __launch_bounds__(AGG_THREADS, 8)
void k_layer2(const u64* __restrict__ slots, const int* __restrict__ gCnt,
              const float* __restrict__ dinv, const float* __restrict__ z,
              const float* __restrict__ b2, float* __restrict__ out,
              int N, int cap) {
    __shared__ int accs[NPB];
    __shared__ float dLds[NPB];
    layer2_body(slots, gCnt, dinv, z, b2, out, N, cap, blockIdx.x, accs, dLds,
                AGG_THREADS);
}

// ------------------------- fallback (round-1) path -------------------------
__global__ __launch_bounds__(1024)
void k_detect(const unsigned int* __restrict__ idx_words, int nCheck, int* flag) {
    __shared__ int cnt;
    if (threadIdx.x == 0) cnt = 0;
    __syncthreads();
    int local = 0;
    for (int i = threadIdx.x; i < nCheck; i += blockDim.x)
        local += (idx_words[2 * i + 1] != 0u) ? 1 : 0;
    if (local) atomicAdd(&cnt, local);
    __syncthreads();
    if (threadIdx.x == 0) *flag = (cnt < 8) ? 1 : 0;
}

__global__ __launch_bounds__(256)
void k_init(float* __restrict__ deg, int N) {
    int i = blockIdx.x * blockDim.x + threadIdx.x;
    if (i < N) deg[i] = 1.0f;
}

__global__ __launch_bounds__(256)
void k_deg(const void* __restrict__ idx, const float* __restrict__ ew,
           float* __restrict__ deg, int E, const int* __restrict__ flag) {
    const bool is64 = (*flag != 0);
    const int stride = gridDim.x * blockDim.x;
    for (int e = blockIdx.x * blockDim.x + threadIdx.x; e < E; e += stride) {
        int d = is64 ? (int)((const long long*)idx)[(long long)E + e]
                     : ((const int*)idx)[E + e];
        atomicAdd(deg + d, ew[e]);
    }
}

__global__ __launch_bounds__(256)
void k_dinv_accx(float* __restrict__ deg_dinv, const float4* __restrict__ x,
                 float4* __restrict__ accx, int N) {
    int n = blockIdx.x * blockDim.x + threadIdx.x;
    if (n >= N) return;
    float dg = deg_dinv[n];
    float di = (dg > 0.0f) ? rsqrtf(dg) : 0.0f;
    deg_dinv[n] = di;
    float sn = di * di;
    float4 xv = x[n];
    accx[n] = make_float4(xv.x * sn, xv.y * sn, xv.z * sn, xv.w * sn);
}

__global__ __launch_bounds__(256)
void k_scatter1(const void* __restrict__ idx, const float* __restrict__ ew,
                const float* __restrict__ dinv, const float4* __restrict__ x,
                float* __restrict__ accx, int E, const int* __restrict__ flag) {
    const bool is64 = (*flag != 0);
    const int stride = gridDim.x * blockDim.x;
    for (int e = blockIdx.x * blockDim.x + threadIdx.x; e < E; e += stride) {
        int s, d;
        if (is64) {
            const long long* p = (const long long*)idx;
            s = (int)p[e]; d = (int)p[(long long)E + e];
        } else {
            const int* p = (const int*)idx;
            s = p[e]; d = p[E + e];
        }
        float nm = dinv[s] * ew[e] * dinv[d];
        float4 xv = x[s];
        float* dp = accx + (size_t)d * 4;
        atomicAdd(dp + 0, nm * xv.x);
        atomicAdd(dp + 1, nm * xv.y);
        atomicAdd(dp + 2, nm * xv.z);
        atomicAdd(dp + 3, nm * xv.w);
    }
}

__global__ __launch_bounds__(256)
void k_node2(const float4* __restrict__ accx, const float* __restrict__ dinv,
             const float* __restrict__ W1, const float* __restrict__ b1,
             const float* __restrict__ W2, const float* __restrict__ b2,
             float* __restrict__ s2, float* __restrict__ out, int N) {
    __shared__ float sW1[64], sb1[16], sW2[16];
    if (threadIdx.x < 64) sW1[threadIdx.x] = W1[threadIdx.x];
    if (threadIdx.x < 16) {
        sb1[threadIdx.x] = b1[threadIdx.x];
        sW2[threadIdx.x] = W2[threadIdx.x];
    }
    __syncthreads();
    int n = blockIdx.x * blockDim.x + threadIdx.x;
    if (n >= N) return;
    float bb2 = b2[0];
    float4 a = accx[n];
    float acc = 0.0f;
#pragma unroll
    for (int k = 0; k < 16; ++k) {
        float h = a.x * sW1[k] + a.y * sW1[16 + k] + a.z * sW1[32 + k]
                + a.w * sW1[48 + k] + sb1[k];
        acc += fmaxf(h, 0.0f) * sW2[k];
    }
    s2[n] = acc;
    float di = dinv[n];
    out[n] = acc * di * di + bb2;
}

__global__ __launch_bounds__(256)
void k_scatter2(const void* __restrict__ idx, const float* __restrict__ ew,
                const float* __restrict__ dinv, const float* __restrict__ s2,
                float* __restrict__ out, int E, const int* __restrict__ flag) {
    const bool is64 = (*flag != 0);
    const int stride = gridDim.x * blockDim.x;
    for (int e = blockIdx.x * blockDim.x + threadIdx.x; e < E; e += stride) {
        int s, d;
        if (is64) {
            const long long* p = (const long long*)idx;
            s = (int)p[e]; d = (int)p[(long long)E + e];
        } else {
            const int* p = (const int*)idx;
            s = p[e]; d = p[E + e];
        }
        float nm = dinv[s] * ew[e] * dinv[d];
        atomicAdd(out + d, nm * s2[s]);
    }
}

// ---------------------------------------------------------------------------
extern "C" void kernel_launch(void* const* d_in, const int* in_sizes, int n_in,
                              void* d_out, int out_size, void* d_ws, size_t ws_size,
                              hipStream_t stream) {
    const float* x   = (const float*)d_in[0];
    const void*  eix = d_in[1];
    const float* ew  = (const float*)d_in[2];
    const float* W1  = (const float*)d_in[3];
    const float* b1  = (const float*)d_in[4];
    const float* W2  = (const float*)d_in[5];
    const float* b2  = (const float*)d_in[6];
    float* out = (float*)d_out;

    const int N = in_sizes[0] / 4;   // x is [N,4]
    const int E = in_sizes[2];       // edge_weight is [E]

    const int B = (N + NPB - 1) >> NPB_SHIFT;
    int cap = (E / B + 2048 + 7) & ~7;   // mean + ~23 sigma, multiple of 8
    const int nCheck = (E < 65536) ? E : 65536;

    // ws: y h4[N] | slots u64[B*cap] | gCnt[B] | rowCnt[N] | dinv[N] | z[N] | flag
    size_t need = (size_t)N * 8 + (size_t)B * cap * 8
                + (size_t)B * 4 + (size_t)N * 12 + 256;

    bool addr32ok = ((long long)B * cap) < 0xFFFFFFFFLL;

    if (B <= MAX_BINS && N < (1 << 23) && ws_size >= need && addr32ok) {
        h4* y = (h4*)d_ws;
        u64* slots = (u64*)(y + N);
        int*   gCnt = (int*)(slots + (size_t)B * cap);
        int*   rowCnt = gCnt + B;
        float* dinv = (float*)(rowCnt + N);
        float* z    = dinv + N;
        int*   flag = (int*)(z + N);

        const int part_blocks = (E + PART_CHUNK - 1) / PART_CHUNK;

        k_prep<<<2, 1024, 0, stream>>>((const unsigned int*)eix, nCheck, flag,
                                       gCnt, B, 2);
        k_partition<<<part_blocks, PART_THREADS, 0, stream>>>(eix, ew, gCnt, slots,
                                                              E, B, cap, flag);

        // Fused cooperative agg; fall back to split kernels if it won't launch.
        const float4* x4 = (const float4*)x;
        int Nv = N, capv = cap, Bv = B;
        hipError_t cerr = hipErrorUnknown;
        int maxPerCU = 0;
        if (hipOccupancyMaxActiveBlocksPerMultiprocessor(&maxPerCU, k_agg,
                                                         FUSE_THREADS, 0)
                == hipSuccess && maxPerCU > 0) {
            int fuseBlocks = maxPerCU * 256;
            if (fuseBlocks > FUSE_BLOCKS) fuseBlocks = FUSE_BLOCKS;
            if (fuseBlocks > B) fuseBlocks = B;
            void* args[] = {(void*)&slots, (void*)&gCnt, (void*)&x4,
                            (void*)&W1, (void*)&b1, (void*)&W2, (void*)&b2,
                            (void*)&dinv, (void*)&y, (void*)&rowCnt,
                            (void*)&z, (void*)&out,
                            (void*)&Nv, (void*)&capv, (void*)&Bv};
            cerr = hipLaunchCooperativeKernel((void*)k_agg, dim3(fuseBlocks),
                                              dim3(FUSE_THREADS), args, 0, stream);
        }
        if (cerr != hipSuccess) {
            k_deg_dinv<<<B, AGG_THREADS, 0, stream>>>(slots, gCnt, x4,
                                                      dinv, y, rowCnt, N, cap);
            k_layer1<<<B, AGG_THREADS, 0, stream>>>(slots, gCnt, dinv, y, rowCnt,
                                                    W1, b1, W2, z, N, cap);
            k_layer2<<<B, AGG_THREADS, 0, stream>>>(slots, gCnt, dinv, z, b2,
                                                    out, N, cap);
        }
    } else {
        // fallback: direct atomic scatter (round-1)
        const int nb_n = (N + 255) / 256;
        const int nb_e = min((E + 255) / 256, 16384);
        float* deg  = (float*)d_ws;
        float* accx = deg + N;
        float* s2   = accx + (size_t)4 * N;
        int*   flag = (int*)(s2 + N);

        k_init<<<nb_n, 256, 0, stream>>>(deg, N);
        k_detect<<<1, 1024, 0, stream>>>((const unsigned int*)eix, nCheck, flag);
        k_deg<<<nb_e, 256, 0, stream>>>(eix, ew, deg, E, flag);
        k_dinv_accx<<<nb_n, 256, 0, stream>>>(deg, (const float4*)x, (float4*)accx, N);
        k_scatter1<<<nb_e, 256, 0, stream>>>(eix, ew, deg, (const float4*)x, accx, E, flag);
        k_node2<<<nb_n, 256, 0, stream>>>((const float4*)accx, deg, W1, b1, W2, b2, s2, out, N);
        k_scatter2<<<nb_e, 256, 0, stream>>>(eix, ew, deg, s2, out, E, flag);
    }
}

// Round 22
// 179.273 us; speedup vs baseline: 1.4824x; 1.4824x over previous
//
#include <hip/hip_runtime.h>
#include <hip/hip_fp16.h>

// ---------------------------------------------------------------------------
// CrowdGNN: 2-layer GCN, N=500k nodes, E=8M edges (+ implicit self loops).
// Round-22 = REVERT to round-20 champion (179.2us). Round-21's cooperative
// fusion regressed 179->266us: grid capped at 512 blocks (vs B=977) made
// each block serialize ~2 bins/phase behind block barriers, grid.sync cost
// more than the 2 kernel boundaries it removed, occupancy fell to 46%.
// Kernel-boundary overhead is measured-negligible; agg kernels sit at the
// LDS-atomic-rate + stream floor; partition at ~55us after 3 structural
// reductions (further chunk-doubling blocked by LDS capacity).
// Pipeline: prep -> partition (16K-edge blocks, bin-in-payload, LDS
// bin-sorted staging) -> deg/dinv/y (8-wide) -> layer1 (u64-packed
// 2-atomic/edge) -> layer2 (8-wide, 1 atomic/edge).
// Fixed-point: wq q11 in slot hi (bin10|wq11); y fp16; acc q22/q20.
// ---------------------------------------------------------------------------

typedef unsigned long long u64;
typedef long long ll2 __attribute__((ext_vector_type(2)));

#define NPB_SHIFT 9
#define NPB 512
#define MAX_BINS 1024
#define PART_THREADS 1024
#define PART_EPT 16
#define PART_CHUNK (PART_THREADS * PART_EPT)   // 16384 edges per block
#define AGG_THREADS 512

#define Q11      2048.0f
#define INV11    (1.0f / 2048.0f)
#define A1_INV   (1.0f / 4194304.0f)   // q22
#define A2_INV   (1.0f / 1048576.0f)   // q20
#define BIAS     (1u << 25)            // per-edge field bias, > max|c|=2^24.4
#define WQMASK   0x7FFu

struct h4 { __half2 a, b; };

__device__ __forceinline__ float4 h4_to_f4(h4 v) {
    float2 lo = __half22float2(v.a);
    float2 hi = __half22float2(v.b);
    return make_float4(lo.x, lo.y, hi.x, hi.y);
}

// One launch: zero gCnt (all threads) + int64/int32 detect (block 0).
__global__ __launch_bounds__(1024)
void k_prep(const unsigned int* __restrict__ idx_words, int nCheck, int* flag,
            int* __restrict__ gCnt, int B, int nBlocks) {
    int gid = blockIdx.x * 1024 + threadIdx.x;
    for (int i = gid; i < B; i += nBlocks * 1024) gCnt[i] = 0;
    if (blockIdx.x == 0) {
        __shared__ int cnt;
        if (threadIdx.x == 0) cnt = 0;
        __syncthreads();
        int local = 0;
        for (int i = threadIdx.x; i < nCheck; i += 1024)
            local += (idx_words[2 * i + 1] != 0u) ? 1 : 0;
        if (local) atomicAdd(&cnt, local);
        __syncthreads();
        if (threadIdx.x == 0) *flag = (cnt < 8) ? 1 : 0;
    }
}

// Bin-sorted-staging partition; payload = [bin10|wq11]<<32 | [dl9|src23].
// 16384 edges/block; address recomputed at store (no sAddr staging).
__global__ __launch_bounds__(PART_THREADS)
void k_partition(const void* __restrict__ idx, const float* __restrict__ ew,
                 int* __restrict__ gCnt, u64* __restrict__ slots,
                 int E, int B, int cap, const int* __restrict__ flag) {
    __shared__ int lcnt[MAX_BINS];
    __shared__ int lbase[MAX_BINS];
    __shared__ int lstart[MAX_BINS];
    __shared__ u64 sPay[PART_CHUNK];
    __shared__ int waveSum[PART_THREADS / 64];

    const bool is64 = (*flag != 0);
    const int tid = threadIdx.x;
    for (int i = tid; i < MAX_BINS; i += PART_THREADS) lcnt[i] = 0;
    __syncthreads();

    const int base_e = blockIdx.x * PART_CHUNK;
    const int nValid = min(PART_CHUNK, E - base_e);

    u64 pay[PART_EPT];
    int r_[PART_EPT];
#pragma unroll
    for (int i = 0; i < PART_EPT; ++i) {
        int e = base_e + i * PART_THREADS + tid;
        r_[i] = -1;
        if (e < E) {
            int s, d;
            if (is64) {
                const long long* p = (const long long*)idx;
                s = (int)__builtin_nontemporal_load(p + e);
                d = (int)__builtin_nontemporal_load(p + (long long)E + e);
            } else {
                const int* p = (const int*)idx;
                s = __builtin_nontemporal_load(p + e);
                d = __builtin_nontemporal_load(p + E + e);
            }
            float w = __builtin_nontemporal_load(ew + e);
            int bin = d >> NPB_SHIFT;
            unsigned wq = min((unsigned)__float2int_rn(w * Q11), 2047u);
            unsigned hi = ((unsigned)bin << 11) | wq;            // bin10|wq11
            unsigned pk = ((unsigned)(d & (NPB - 1)) << 23) | (unsigned)s;
            pay[i] = ((u64)hi << 32) | pk;
            r_[i] = atomicAdd(&lcnt[bin], 1);
        }
    }
    __syncthreads();

    {
        const int lane = tid & 63, wid = tid >> 6;
        const int v = lcnt[tid];
        int inc = v;
#pragma unroll
        for (int off = 1; off < 64; off <<= 1) {
            int t = __shfl_up(inc, off, 64);
            if (lane >= off) inc += t;
        }
        if (lane == 63) waveSum[wid] = inc;
        __syncthreads();
        if (wid == 0) {
            const int NW = PART_THREADS / 64;
            int wv = (lane < NW) ? waveSum[lane] : 0;
            int winc = wv;
#pragma unroll
            for (int off = 1; off < NW; off <<= 1) {
                int t = __shfl_up(winc, off, 64);
                if (lane >= off) winc += t;
            }
            if (lane < NW) waveSum[lane] = winc - wv;
        }
        __syncthreads();
        lstart[tid] = inc - v + waveSum[wid];
        lbase[tid] = (v > 0 && tid < B) ? atomicAdd(&gCnt[tid], v) : 0;
    }
    __syncthreads();

    // Stage in bin-sorted order (payload only).
#pragma unroll
    for (int i = 0; i < PART_EPT; ++i) {
        if (r_[i] >= 0) {
            int bin = (int)(pay[i] >> 43);
            sPay[lstart[bin] + r_[i]] = pay[i];
        }
    }
    __syncthreads();

    // Coalesced store; address from bin-id in payload + lbase/lstart.
    for (int k = tid; k < nValid; k += PART_THREADS) {
        u64 v = sPay[k];
        int bin = (int)(v >> 43);
        long long pos = (long long)lbase[bin] + (k - lstart[bin]);
        if (pos < cap) slots[(size_t)bin * cap + pos] = v;
    }
}

// 4-wide slot fetch, CACHED loads (nt measured -12us worse on this stream).
__device__ __forceinline__ void load4(const u64* __restrict__ sp, int j, int c,
                                      u64& v0, u64& v1, u64& v2, u64& v3) {
    v0 = v1 = v2 = v3 = 0;
    if (j + 3 < c) {
        ll2 q0 = *((const ll2*)(sp + j));
        ll2 q1 = *((const ll2*)(sp + j) + 1);
        v0 = (u64)q0.x; v1 = (u64)q0.y; v2 = (u64)q1.x; v3 = (u64)q1.y;
    } else if (j < c) {
        v0 = sp[j];
        if (j + 1 < c) v1 = sp[j + 1];
        if (j + 2 < c) v2 = sp[j + 2];
    }
}

// 8-wide slot fetch; tail zero-filled (consumers predicate where needed).
__device__ __forceinline__ void load8(const u64* __restrict__ sp, int j, int c,
                                      u64* __restrict__ v) {
    if (j + 7 < c) {
#pragma unroll
        for (int q = 0; q < 4; ++q) {
            ll2 t = *((const ll2*)(sp + j) + q);
            v[2 * q]     = (u64)t.x;
            v[2 * q + 1] = (u64)t.y;
        }
    } else {
#pragma unroll
        for (int q = 0; q < 8; ++q)
            v[q] = (j + q < c) ? sp[j + q] : 0ULL;
    }
}

// Per-bin: deg/count via packed (1<<20)|wq atomics (PREDICATED — counts must
// be exact for layer1's bias removal); dinv; y = fp16(x*dinv); rowCnt.
// 8-wide ILP: 4x16B loads + 8 independent atomic chains per thread.
__global__ __launch_bounds__(AGG_THREADS, 8)
void k_deg_dinv(const u64* __restrict__ slots, const int* __restrict__ gCnt,
                const float4* __restrict__ x, float* __restrict__ dinv,
                h4* __restrict__ y, int* __restrict__ rowCnt, int N, int cap) {
    __shared__ unsigned degLds[NPB];
    const int b = blockIdx.x;
    for (int t = threadIdx.x; t < NPB; t += AGG_THREADS) degLds[t] = 0u;
    __syncthreads();
    const int c = min(gCnt[b], cap);
    const u64* sp = slots + (size_t)b * cap;
    const int CH = AGG_THREADS * 8;
    for (int base = 0; base < c; base += CH) {
        int j = base + (threadIdx.x << 3);
        u64 v[8];
        load8(sp, j, c, v);
#pragma unroll
        for (int q = 0; q < 8; ++q) {
            if (j + q < c)
                atomicAdd(&degLds[((unsigned)v[q]) >> 23],
                          (1u << 20) | ((unsigned)(v[q] >> 32) & WQMASK));
        }
    }
    __syncthreads();
    for (int t = threadIdx.x; t < NPB; t += AGG_THREADS) {
        int n = (b << NPB_SHIFT) + t;
        if (n < N) {
            unsigned dc = degLds[t];
            float di = rsqrtf(1.0f + (float)(dc & 0xFFFFFu) * INV11);
            dinv[n] = di;
            rowCnt[n] = (int)(dc >> 20);
            float4 xv = x[n];
            h4 hv;
            hv.a = __floats2half2_rn(xv.x * di, xv.y * di);
            hv.b = __floats2half2_rn(xv.z * di, xv.w * di);
            y[n] = hv;
        }
    }
}

// Per-bin layer1: u64-packed LDS atomics (2/edge), biased fields; fused MLP.
__global__ __launch_bounds__(AGG_THREADS, 4)
void k_layer1(const u64* __restrict__ slots, const int* __restrict__ gCnt,
              const float* __restrict__ dinv, const h4* __restrict__ yh,
              const int* __restrict__ rowCnt, const float* __restrict__ W1,
              const float* __restrict__ b1, const float* __restrict__ W2,
              float* __restrict__ z, int N, int cap) {
    __shared__ u64 acc2[NPB][2];    // [n][0]=ch0|ch1, [n][1]=ch2|ch3 (biased)
    __shared__ float dLds[NPB];
    __shared__ float sW1[64], sb1[16], sW2[16];
    if (threadIdx.x < 64) sW1[threadIdx.x] = W1[threadIdx.x];
    if (threadIdx.x < 16) {
        sb1[threadIdx.x] = b1[threadIdx.x];
        sW2[threadIdx.x] = W2[threadIdx.x];
    }
    const int b = blockIdx.x;
    for (int t = threadIdx.x; t < NPB; t += AGG_THREADS) {
        acc2[t][0] = 0ULL; acc2[t][1] = 0ULL;
        int n = (b << NPB_SHIFT) + t;
        dLds[t] = (n < N) ? dinv[n] : 0.0f;
    }
    __syncthreads();
    const int c = min(gCnt[b], cap);
    const u64* sp = slots + (size_t)b * cap;
    const int CH = AGG_THREADS * 4;
    for (int base = 0; base < c; base += CH) {
        int j = base + (threadIdx.x << 2);
        u64 v0, v1, v2, v3;
        load4(sp, j, c, v0, v1, v2, v3);
        unsigned pk0 = (unsigned)v0, pk1 = (unsigned)v1,
                 pk2 = (unsigned)v2, pk3 = (unsigned)v3;
        // wq*y*2048 == (wq/2048)*y*2^22 -> q22 contribution
        float w0 = (float)((unsigned)(v0 >> 32) & WQMASK) * 2048.0f;
        float w1 = (float)((unsigned)(v1 >> 32) & WQMASK) * 2048.0f;
        float w2 = (float)((unsigned)(v2 >> 32) & WQMASK) * 2048.0f;
        float w3 = (float)((unsigned)(v3 >> 32) & WQMASK) * 2048.0f;
        // 4 independent gathers in flight (cached; y table is 4MB)
        h4 g0 = yh[pk0 & 0x7FFFFF];
        h4 g1 = yh[pk1 & 0x7FFFFF];
        h4 g2 = yh[pk2 & 0x7FFFFF];
        h4 g3 = yh[pk3 & 0x7FFFFF];
        float4 f0 = h4_to_f4(g0), f1 = h4_to_f4(g1),
               f2 = h4_to_f4(g2), f3 = h4_to_f4(g3);
        int d0 = pk0 >> 23, d1 = pk1 >> 23, d2 = pk2 >> 23, d3 = pk3 >> 23;
#define PACK2(wf, fa, fb) \
        (((u64)(unsigned)(__float2int_rn((wf) * (fb)) + (int)BIAS) << 32) | \
          (u64)(unsigned)(__float2int_rn((wf) * (fa)) + (int)BIAS))
        if (j < c) {
            atomicAdd(&acc2[d0][0], PACK2(w0, f0.x, f0.y));
            atomicAdd(&acc2[d0][1], PACK2(w0, f0.z, f0.w));
        }
        if (j + 1 < c) {
            atomicAdd(&acc2[d1][0], PACK2(w1, f1.x, f1.y));
            atomicAdd(&acc2[d1][1], PACK2(w1, f1.z, f1.w));
        }
        if (j + 2 < c) {
            atomicAdd(&acc2[d2][0], PACK2(w2, f2.x, f2.y));
            atomicAdd(&acc2[d2][1], PACK2(w2, f2.z, f2.w));
        }
        if (j + 3 < c) {
            atomicAdd(&acc2[d3][0], PACK2(w3, f3.x, f3.y));
            atomicAdd(&acc2[d3][1], PACK2(w3, f3.z, f3.w));
        }
#undef PACK2
    }
    __syncthreads();
    for (int t = threadIdx.x; t < NPB; t += AGG_THREADS) {
        int n = (b << NPB_SHIFT) + t;
        if (n >= N) continue;
        unsigned cb = (unsigned)rowCnt[n] * BIAS;
        u64 p01 = acc2[t][0], p23 = acc2[t][1];
        int a0 = (int)((unsigned)(p01 & 0xFFFFFFFFu) - cb);
        int a1 = (int)((unsigned)(p01 >> 32) - cb);
        int a2 = (int)((unsigned)(p23 & 0xFFFFFFFFu) - cb);
        int a3 = (int)((unsigned)(p23 >> 32) - cb);
        float di = dLds[t];
        float4 yv = h4_to_f4(yh[n]);
        float ax = di * (yv.x + (float)a0 * A1_INV);
        float ay = di * (yv.y + (float)a1 * A1_INV);
        float az = di * (yv.z + (float)a2 * A1_INV);
        float aw = di * (yv.w + (float)a3 * A1_INV);
        float sacc = 0.0f;
#pragma unroll
        for (int k = 0; k < 16; ++k) {
            float h = ax * sW1[k] + ay * sW1[16 + k] + az * sW1[32 + k]
                    + aw * sW1[48 + k] + sb1[k];
            sacc += fmaxf(h, 0.0f) * sW2[k];
        }
        z[n] = sacc * di;
    }
}

// Per-bin layer2: out[n] = di*(z[n] + sum w*z[s]) + b2. 1 atomic/edge;
// sentinel wq=0 contributes 0 -> unconditional adds are safe. 8-wide ILP.
__global__ __launch_bounds__(AGG_THREADS, 8)
void k_layer2(const u64* __restrict__ slots, const int* __restrict__ gCnt,
              const float* __restrict__ dinv, const float* __restrict__ z,
              const float* __restrict__ b2, float* __restrict__ out,
              int N, int cap) {
    __shared__ int accs[NPB];
    __shared__ float dLds[NPB];
    const int b = blockIdx.x;
    for (int t = threadIdx.x; t < NPB; t += AGG_THREADS) {
        accs[t] = 0;
        int n = (b << NPB_SHIFT) + t;
        dLds[t] = (n < N) ? dinv[n] : 0.0f;
    }
    __syncthreads();
    const int c = min(gCnt[b], cap);
    const u64* sp = slots + (size_t)b * cap;
    const int CH = AGG_THREADS * 8;
    for (int base = 0; base < c; base += CH) {
        int j = base + (threadIdx.x << 3);
        u64 v[8];
        load8(sp, j, c, v);
        float zf[8];
#pragma unroll
        for (int q = 0; q < 8; ++q)
            zf[q] = z[(unsigned)v[q] & 0x7FFFFF];   // 8 independent gathers
#pragma unroll
        for (int q = 0; q < 8; ++q) {
            // w*z*2^20 = wq*z*512 ; sentinel v=0 -> wq=0 -> adds 0
            atomicAdd(&accs[((unsigned)v[q]) >> 23],
                      __float2int_rn((float)((unsigned)(v[q] >> 32) & WQMASK)
                                     * zf[q] * 512.0f));
        }
    }
    __syncthreads();
    const float bb2 = b2[0];
    for (int t = threadIdx.x; t < NPB; t += AGG_THREADS) {
        int n = (b << NPB_SHIFT) + t;
        if (n < N) out[n] = dLds[t] * (z[n] + (float)accs[t] * A2_INV) + bb2;
    }
}

// ------------------------- fallback (round-1) path -------------------------
__global__ __launch_bounds__(1024)
void k_detect(const unsigned int* __restrict__ idx_words, int nCheck, int* flag) {
    __shared__ int cnt;
    if (threadIdx.x == 0) cnt = 0;
    __syncthreads();
    int local = 0;
    for (int i = threadIdx.x; i < nCheck; i += blockDim.x)
        local += (idx_words[2 * i + 1] != 0u) ? 1 : 0;
    if (local) atomicAdd(&cnt, local);
    __syncthreads();
    if (threadIdx.x == 0) *flag = (cnt < 8) ? 1 : 0;
}

__global__ __launch_bounds__(256)
void k_init(float* __restrict__ deg, int N) {
    int i = blockIdx.x * blockDim.x + threadIdx.x;
    if (i < N) deg[i] = 1.0f;
}

__global__ __launch_bounds__(256)
void k_deg(const void* __restrict__ idx, const float* __restrict__ ew,
           float* __restrict__ deg, int E, const int* __restrict__ flag) {
    const bool is64 = (*flag != 0);
    const int stride = gridDim.x * blockDim.x;
    for (int e = blockIdx.x * blockDim.x + threadIdx.x; e < E; e += stride) {
        int d = is64 ? (int)((const long long*)idx)[(long long)E + e]
                     : ((const int*)idx)[E + e];
        atomicAdd(deg + d, ew[e]);
    }
}

__global__ __launch_bounds__(256)
void k_dinv_accx(float* __restrict__ deg_dinv, const float4* __restrict__ x,
                 float4* __restrict__ accx, int N) {
    int n = blockIdx.x * blockDim.x + threadIdx.x;
    if (n >= N) return;
    float dg = deg_dinv[n];
    float di = (dg > 0.0f) ? rsqrtf(dg) : 0.0f;
    deg_dinv[n] = di;
    float sn = di * di;
    float4 xv = x[n];
    accx[n] = make_float4(xv.x * sn, xv.y * sn, xv.z * sn, xv.w * sn);
}

__global__ __launch_bounds__(256)
void k_scatter1(const void* __restrict__ idx, const float* __restrict__ ew,
                const float* __restrict__ dinv, const float4* __restrict__ x,
                float* __restrict__ accx, int E, const int* __restrict__ flag) {
    const bool is64 = (*flag != 0);
    const int stride = gridDim.x * blockDim.x;
    for (int e = blockIdx.x * blockDim.x + threadIdx.x; e < E; e += stride) {
        int s, d;
        if (is64) {
            const long long* p = (const long long*)idx;
            s = (int)p[e]; d = (int)p[(long long)E + e];
        } else {
            const int* p = (const int*)idx;
            s = p[e]; d = p[E + e];
        }
        float nm = dinv[s] * ew[e] * dinv[d];
        float4 xv = x[s];
        float* dp = accx + (size_t)d * 4;
        atomicAdd(dp + 0, nm * xv.x);
        atomicAdd(dp + 1, nm * xv.y);
        atomicAdd(dp + 2, nm * xv.z);
        atomicAdd(dp + 3, nm * xv.w);
    }
}

__global__ __launch_bounds__(256)
void k_node2(const float4* __restrict__ accx, const float* __restrict__ dinv,
             const float* __restrict__ W1, const float* __restrict__ b1,
             const float* __restrict__ W2, const float* __restrict__ b2,
             float* __restrict__ s2, float* __restrict__ out, int N) {
    __shared__ float sW1[64], sb1[16], sW2[16];
    if (threadIdx.x < 64) sW1[threadIdx.x] = W1[threadIdx.x];
    if (threadIdx.x < 16) {
        sb1[threadIdx.x] = b1[threadIdx.x];
        sW2[threadIdx.x] = W2[threadIdx.x];
    }
    __syncthreads();
    int n = blockIdx.x * blockDim.x + threadIdx.x;
    if (n >= N) return;
    float bb2 = b2[0];
    float4 a = accx[n];
    float acc = 0.0f;
#pragma unroll
    for (int k = 0; k < 16; ++k) {
        float h = a.x * sW1[k] + a.y * sW1[16 + k] + a.z * sW1[32 + k]
                + a.w * sW1[48 + k] + sb1[k];
        acc += fmaxf(h, 0.0f) * sW2[k];
    }
    s2[n] = acc;
    float di = dinv[n];
    out[n] = acc * di * di + bb2;
}

__global__ __launch_bounds__(256)
void k_scatter2(const void* __restrict__ idx, const float* __restrict__ ew,
                const float* __restrict__ dinv, const float* __restrict__ s2,
                float* __restrict__ out, int E, const int* __restrict__ flag) {
    const bool is64 = (*flag != 0);
    const int stride = gridDim.x * blockDim.x;
    for (int e = blockIdx.x * blockDim.x + threadIdx.x; e < E; e += stride) {
        int s, d;
        if (is64) {
            const long long* p = (const long long*)idx;
            s = (int)p[e]; d = (int)p[(long long)E + e];
        } else {
            const int* p = (const int*)idx;
            s = p[e]; d = p[E + e];
        }
        float nm = dinv[s] * ew[e] * dinv[d];
        atomicAdd(out + d, nm * s2[s]);
    }
}

// ---------------------------------------------------------------------------
extern "C" void kernel_launch(void* const* d_in, const int* in_sizes, int n_in,
                              void* d_out, int out_size, void* d_ws, size_t ws_size,
                              hipStream_t stream) {
    const float* x   = (const float*)d_in[0];
    const void*  eix = d_in[1];
    const float* ew  = (const float*)d_in[2];
    const float* W1  = (const float*)d_in[3];
    const float* b1  = (const float*)d_in[4];
    const float* W2  = (const float*)d_in[5];
    const float* b2  = (const float*)d_in[6];
    float* out = (float*)d_out;

    const int N = in_sizes[0] / 4;   // x is [N,4]
    const int E = in_sizes[2];       // edge_weight is [E]

    const int B = (N + NPB - 1) >> NPB_SHIFT;
    int cap = (E / B + 2048 + 7) & ~7;   // mean + ~23 sigma, multiple of 8
    const int nCheck = (E < 65536) ? E : 65536;

    // ws: y h4[N] | slots u64[B*cap] | gCnt[B] | rowCnt[N] | dinv[N] | z[N] | flag
    size_t need = (size_t)N * 8 + (size_t)B * cap * 8
                + (size_t)B * 4 + (size_t)N * 12 + 256;

    bool addr32ok = ((long long)B * cap) < 0xFFFFFFFFLL;

    if (B <= MAX_BINS && N < (1 << 23) && ws_size >= need && addr32ok) {
        h4* y = (h4*)d_ws;
        u64* slots = (u64*)(y + N);
        int*   gCnt = (int*)(slots + (size_t)B * cap);
        int*   rowCnt = gCnt + B;
        float* dinv = (float*)(rowCnt + N);
        float* z    = dinv + N;
        int*   flag = (int*)(z + N);

        const int part_blocks = (E + PART_CHUNK - 1) / PART_CHUNK;

        k_prep<<<2, 1024, 0, stream>>>((const unsigned int*)eix, nCheck, flag,
                                       gCnt, B, 2);
        k_partition<<<part_blocks, PART_THREADS, 0, stream>>>(eix, ew, gCnt, slots,
                                                              E, B, cap, flag);
        k_deg_dinv<<<B, AGG_THREADS, 0, stream>>>(slots, gCnt, (const float4*)x,
                                                  dinv, y, rowCnt, N, cap);
        k_layer1<<<B, AGG_THREADS, 0, stream>>>(slots, gCnt, dinv, y, rowCnt,
                                                W1, b1, W2, z, N, cap);
        k_layer2<<<B, AGG_THREADS, 0, stream>>>(slots, gCnt, dinv, z, b2, out, N, cap);
    } else {
        // fallback: direct atomic scatter (round-1)
        const int nb_n = (N + 255) / 256;
        const int nb_e = min((E + 255) / 256, 16384);
        float* deg  = (float*)d_ws;
        float* accx = deg + N;
        float* s2   = accx + (size_t)4 * N;
        int*   flag = (int*)(s2 + N);

        k_init<<<nb_n, 256, 0, stream>>>(deg, N);
        k_detect<<<1, 1024, 0, stream>>>((const unsigned int*)eix, nCheck, flag);
        k_deg<<<nb_e, 256, 0, stream>>>(eix, ew, deg, E, flag);
        k_dinv_accx<<<nb_n, 256, 0, stream>>>(deg, (const float4*)x, (float4*)accx, N);
        k_scatter1<<<nb_e, 256, 0, stream>>>(eix, ew, deg, (const float4*)x, accx, E, flag);
        k_node2<<<nb_n, 256, 0, stream>>>((const float4*)accx, deg, W1, b1, W2, b2, s2, out, N);
        k_scatter2<<<nb_e, 256, 0, stream>>>(eix, ew, deg, s2, out, E, flag);
    }
}